// Round 15
// baseline (34.065 us; speedup 1.0000x reference)
//
#include <hip/hip_runtime.h>

// y[b,o] = sum_i weight[o,i] * sin(w[o,i] * xb[b,i]),  xb = [x | 1]
// w[o,i] = (o+1)*2pi/512 const across i. In REVOLUTIONS (v_sin_f32 native):
// arg = (o+1)/512 * x, |arg| <= ~5 << 256, so no v_fract (validated R1-R14).
//
// R15: kill the scalar-delivery stall. R10->R14 showed a CONSTANT ~18us
// stall, insensitive to occupancy/x-layout/pipe/packing — consistent only
// with per-chunk scalar-cache misses: 16 s_load_dwordx4 at 2KB stride =
// 16 lines + lgkmcnt(0) drain per chunk. Fix: transpose weight to
// wT2[i][o] (1MB in ws) so each i's 16 weights are 64 CONTIGUOUS bytes =
// one s_load_dwordx16 -> 4 scalar ops / 4 lines per chunk.
// Math: DOUBLE-STEP Chebyshev, s_{k+2} = 2cos(2*dx)*s_k - s_{k-2}:
// (even,odd) chains are independent -> packed v2f, and the pk weight pair
// {w_{2m}, w_{2m+1}} is adjacent in wT2. Seeds: 3 sin + 1 cos
// (s_{-2} = 2cos(dx)*s_{-1} - s_0 backward step; 2cos2t = (2cost)^2 - 2).
// Chain length halves (7 steps) -> error <= R13's 0.0078.

#define B_TOT 1024
#define IN_D  512
#define OUT_D 512
#define LDW   513              // IN+1
#define O_T   16               // outputs per block
#define NPAIR (O_T / 2)        // 8 packed k-pairs
#define WAVES 8                // i-eighths per block
#define IQ    (IN_D / WAVES)   // 64 i's per wave

typedef float v2f  __attribute__((ext_vector_type(2)));
typedef float v16f __attribute__((ext_vector_type(16)));

// ---- transpose pre-pass: xT[i][b] = x[b][i], 64x64 LDS tiles ----
__global__ __launch_bounds__(256)
void xpose_kernel(const float* __restrict__ x, float* __restrict__ xT)
{
    __shared__ float t[64][65];
    const int i0 = blockIdx.x * 64;
    const int b0 = blockIdx.y * 64;
    const int c  = threadIdx.x & 63;
    const int r0 = threadIdx.x >> 6;   // 0..3
#pragma unroll
    for (int rr = 0; rr < 64; rr += 4) {
        const int r = rr + r0;
        t[r][c] = x[(size_t)(b0 + r) * IN_D + i0 + c];   // coalesced along i
    }
    __syncthreads();
#pragma unroll
    for (int rr = 0; rr < 64; rr += 4) {
        const int r = rr + r0;
        xT[(size_t)(i0 + r) * B_TOT + b0 + c] = t[c][r]; // coalesced along b
    }
}

// ---- weight transpose: wT2[i][o] = weight[o][i], i,o < 512 ----
__global__ __launch_bounds__(256)
void wpose_kernel(const float* __restrict__ wsrc, float* __restrict__ wT2)
{
    __shared__ float t[64][65];
    const int i0 = blockIdx.x * 64;
    const int o0 = blockIdx.y * 64;
    const int c  = threadIdx.x & 63;
    const int r0 = threadIdx.x >> 6;   // 0..3
#pragma unroll
    for (int rr = 0; rr < 64; rr += 4) {
        const int r = rr + r0;
        t[r][c] = wsrc[(size_t)(o0 + r) * LDW + i0 + c]; // coalesced along i
    }
    __syncthreads();
#pragma unroll
    for (int rr = 0; rr < 64; rr += 4) {
        const int r = rr + r0;
        wT2[(size_t)(i0 + r) * OUT_D + o0 + c] = t[c][r];// coalesced along o
    }
}

// ---- main kernel ----
// FAST: x = xT (coalesced), weights via wT2 (one s_load_dwordx16 per i).
// !FAST: x row reads, weights via 16x float4 s_loads (correctness fallback).
template <bool FAST>
__global__ __launch_bounds__(512, 4)
void skan_kernel(const float* __restrict__ x,
                 const float* __restrict__ weight,
                 const float* __restrict__ w,
                 const float* __restrict__ wT2,
                 float* __restrict__ out)
{
    __shared__ float red[WAVES][64][O_T + 1];   // 34.8 KB; stride 17 (2-way max)

    const int tid  = threadIdx.x;
    const int lane = tid & 63;
    const int b0   = blockIdx.y * 64;
    const int o0   = blockIdx.x * O_T;   // uniform (SGPR) by construction
    const int iq   = __builtin_amdgcn_readfirstlane(tid >> 6);
    const int i0   = iq * IQ;

    const float inv2pi = 0.15915493667125702f;
    // frequencies from w (don't assume the ramp): g1=(o0+1)/512, delta=1/512
    const float g1    = w[(size_t)o0 * LDW] * inv2pi;
    const float delta = w[(size_t)(o0 + 1) * LDW] * inv2pi - g1;
    const float gm1   = g1 - delta;
    const float gp1   = g1 + delta;

    // XT path: consecutive lanes -> consecutive addresses (one 256B txn)
    const float* __restrict__ xc   = x + (size_t)i0 * B_TOT + b0 + lane;
    // fallback path: own-row reads
    const float* __restrict__ xrow = x + (size_t)(b0 + lane) * IN_D + i0;

    v2f acc[NPAIR];   // acc[m] = (partial for k=2m, k=2m+1)
#pragma unroll
    for (int m = 0; m < NPAIR; ++m) acc[m] = (v2f)0.0f;

    float nx[4];
#pragma unroll
    for (int j = 0; j < 4; ++j)
        nx[j] = FAST ? xc[(size_t)j * B_TOT] : xrow[j];

    for (int ii = 0; ii < IQ; ii += 4) {
        float xk[4];
#pragma unroll
        for (int j = 0; j < 4; ++j) xk[j] = nx[j];
        if (ii + 4 < IQ) {   // uniform branch; 1-chunk-deep x prefetch
#pragma unroll
            for (int j = 0; j < 4; ++j)
                nx[j] = FAST ? xc[(size_t)(ii + 4 + j) * B_TOT]
                             : xrow[ii + 4 + j];
        }

        // weights: FAST -> 4x s_load_dwordx16 (k-contiguous, 1 line each);
        //          fallback -> 16x s_load_dwordx4 (original layout)
        v16f wv[4];
        float4 wt[O_T];
        if (FAST) {
#pragma unroll
            for (int j = 0; j < 4; ++j)
                wv[j] = *reinterpret_cast<const v16f*>(
                            wT2 + (size_t)(i0 + ii + j) * OUT_D + o0);
        } else {
#pragma unroll
            for (int k = 0; k < O_T; ++k)
                wt[k] = *reinterpret_cast<const float4*>(
                            weight + (size_t)(o0 + k) * LDW + i0 + ii);
        }

#pragma unroll
        for (int j = 0; j < 4; ++j) {
            const float xv = xk[j];
            // double-step Chebyshev setup: 3 sin + 1 cos
            const float dx  = delta * xv;                      // v_mul
            const float c1  = __builtin_amdgcn_cosf(dx);       // v_cos
            const float c21 = c1 + c1;                         // 2cos(dx)
            const float C2  = fmaf(c21, c21, -2.0f);           // 2cos(2dx)
            const float sm1 = __builtin_amdgcn_sinf(gm1 * xv); // s_{-1}
            const float s0  = __builtin_amdgcn_sinf(g1  * xv); // s_0
            const float s1  = __builtin_amdgcn_sinf(gp1 * xv); // s_1
            const float sm2 = fmaf(c21, sm1, -s0);             // s_{-2}
            v2f P  = {s0, s1};     // (s_{2m}, s_{2m+1}) at m=0
            v2f Pm = {sm2, sm1};   // previous pair (m=-1)
            const v2f C2v = {C2, C2};

            const v2f* wp = FAST
                ? reinterpret_cast<const v2f*>(&wv[j]) : nullptr;

            {
                const v2f w0 = FAST ? wp[0]
                    : (v2f){(&wt[0].x)[j], (&wt[1].x)[j]};
                acc[0] = __builtin_elementwise_fma(w0, P, acc[0]);
            }
#pragma unroll
            for (int m = 1; m < NPAIR; ++m) {
                const v2f Pn = __builtin_elementwise_fma(C2v, P, -Pm);
                const v2f wm = FAST ? wp[m]
                    : (v2f){(&wt[2 * m].x)[j], (&wt[2 * m + 1].x)[j]};
                acc[m] = __builtin_elementwise_fma(wm, Pn, acc[m]);
                Pm = P; P = Pn;
            }
        }
    }

    // cross-wave reduction (the only barrier in the kernel)
#pragma unroll
    for (int m = 0; m < NPAIR; ++m) {
        red[iq][lane][2 * m]     = acc[m].x;
        red[iq][lane][2 * m + 1] = acc[m].y;
    }
    __syncthreads();

    // epilogue: 512 threads -> 64 b x 16 k = 1024 outputs, 2 per thread;
    // fold bias column (xb = 1)
    {
        const int b  = tid & 63;
        const int k2 = tid >> 6;           // 0..7 -> k = 2*k2, 2*k2+1
        float2 res;
        float* rp = &res.x;
#pragma unroll
        for (int kk = 0; kk < 2; ++kk) {
            const int k = k2 * 2 + kk;
            float s = 0.0f;
#pragma unroll
            for (int p = 0; p < WAVES; ++p) s += red[p][b][k];
            const int o = o0 + k;
            const float gb = w[(size_t)o * LDW + IN_D] * inv2pi;  // (0,1] rev
            s = fmaf(weight[(size_t)o * LDW + IN_D],
                     __builtin_amdgcn_sinf(gb), s);
            rp[kk] = s;
        }
        *reinterpret_cast<float2*>(
            out + (size_t)(b0 + b) * OUT_D + o0 + k2 * 2) = res;
    }
}

extern "C" void kernel_launch(void* const* d_in, const int* in_sizes, int n_in,
                              void* d_out, int out_size, void* d_ws, size_t ws_size,
                              hipStream_t stream) {
    const float* x      = (const float*)d_in[0];
    const float* weight = (const float*)d_in[1];
    const float* w      = (const float*)d_in[2];
    float* out          = (float*)d_out;

    dim3 grid(OUT_D / O_T, B_TOT / 64);   // (32, 16) = 512 blocks x 512 thr

    const size_t wT2_bytes = (size_t)IN_D * OUT_D * sizeof(float);   // 1 MB
    const size_t xT_bytes  = (size_t)IN_D * B_TOT * sizeof(float);   // 2 MB

    if (ws_size >= wT2_bytes + xT_bytes) {
        float* wT2 = (float*)d_ws;
        float* xT  = (float*)((char*)d_ws + wT2_bytes);
        dim3 wg(IN_D / 64, OUT_D / 64);   // (8, 8)
        dim3 tg(IN_D / 64, B_TOT / 64);   // (8, 16)
        wpose_kernel<<<wg, 256, 0, stream>>>(weight, wT2);
        xpose_kernel<<<tg, 256, 0, stream>>>(x, xT);
        skan_kernel<true><<<grid, 512, 0, stream>>>(xT, weight, w, wT2, out);
    } else {
        skan_kernel<false><<<grid, 512, 0, stream>>>(x, weight, w, nullptr, out);
    }
}

// Round 16
// 27.808 us; speedup vs baseline: 1.2250x; 1.2250x over previous
//
#include <hip/hip_runtime.h>

// y[b,o] = sum_i weight[o,i] * sin(w[o,i] * xb[b,i]),  xb = [x | 1]
// w[o,i] = (o+1)*2pi/512 const across i. In REVOLUTIONS (v_sin_f32 native):
// arg = (o+1)/512 * x, |arg| <= ~5 << 256, so no v_fract (validated R1-R15).
//
// R16 = R13 (champion, 27.05us) + ONE lever: fneg-free packed Chebyshev.
// R13's chain fma(c2, sc, -sp) has a v2f fneg -> plausible v_pk_fma_f32
// emission blocker (ISel must fold into neg_lo/neg_hi or scalarize).
// Sign-twisted recurrence removes it: t_k = sigma_k * s_k,
// sigma_k = (-1)^floor(k/2), then
//   t_{k+1} = fma(C, t_k, t_{k-1}),  C alternating {c2, -c2} (both
//   precomputed, loop-invariant per i) — NO register negation in chain.
// sigma_k is compile-time per k -> folded into the epilogue red-write.
// Same op count & numerics as R13 (absmax 0.0078); pure-fma v2f chain is
// the cleanest possible pattern for pk codegen.

#define B_TOT 1024
#define IN_D  512
#define OUT_D 512
#define LDW   513              // IN+1
#define O_T   16               // outputs per block (15 recurrence steps)
#define WAVES 8                // i-eighths per block
#define IQ    (IN_D / WAVES)   // 64 i's per wave

typedef float v2f __attribute__((ext_vector_type(2)));

// ---- transpose pre-pass: xT[i][b] = x[b][i], 64x64 LDS tiles ----
__global__ __launch_bounds__(256)
void xpose_kernel(const float* __restrict__ x, float* __restrict__ xT)
{
    __shared__ float t[64][65];
    const int i0 = blockIdx.x * 64;
    const int b0 = blockIdx.y * 64;
    const int c  = threadIdx.x & 63;
    const int r0 = threadIdx.x >> 6;   // 0..3
#pragma unroll
    for (int rr = 0; rr < 64; rr += 4) {
        const int r = rr + r0;
        t[r][c] = x[(size_t)(b0 + r) * IN_D + i0 + c];   // coalesced along i
    }
    __syncthreads();
#pragma unroll
    for (int rr = 0; rr < 64; rr += 4) {
        const int r = rr + r0;
        xT[(size_t)(i0 + r) * B_TOT + b0 + c] = t[c][r]; // coalesced along b
    }
}

// ---- main kernel; XT = x transposed in d_ws (coalesced reads) ----
template <bool XT>
__global__ __launch_bounds__(512, 4)
void skan_kernel(const float* __restrict__ x,
                 const float* __restrict__ weight,
                 const float* __restrict__ w,
                 float* __restrict__ out)
{
    __shared__ float red[WAVES][64][O_T + 1];   // 34.8 KB; stride 17 (2-way max)

    const int tid  = threadIdx.x;
    const int lane = tid & 63;
    const int b0   = blockIdx.y * 64;
    const int o0   = blockIdx.x * O_T;   // uniform (SGPR) by construction
    const int iq   = __builtin_amdgcn_readfirstlane(tid >> 6);
    const int i0   = iq * IQ;

    const float inv2pi = 0.15915493667125702f;
    // frequencies from w (don't assume the ramp): g1=(o0+1)/512, delta=1/512
    const float g1    = w[(size_t)o0 * LDW] * inv2pi;
    const float delta = w[(size_t)(o0 + 1) * LDW] * inv2pi - g1;
    const float gp1   = g1 + delta;      // frequency for k = 1

    // ONE scalar base; all weight accesses are imm offsets -> s_load_dwordx4
    const float* __restrict__ wbase = weight + (size_t)o0 * LDW + i0;

    // XT path: consecutive lanes -> consecutive addresses (one 256B txn)
    const float* __restrict__ xc   = x + (size_t)i0 * B_TOT + b0 + lane;
    // fallback path: own-row reads
    const float* __restrict__ xrow = x + (size_t)(b0 + lane) * IN_D + i0;

    v2f acc[O_T];   // packed over i-pairs; both halves are partial i-sums
#pragma unroll
    for (int k = 0; k < O_T; ++k) acc[k] = (v2f)0.0f;

    float nx[4];
#pragma unroll
    for (int j = 0; j < 4; ++j)
        nx[j] = XT ? xc[(size_t)j * B_TOT] : xrow[j];

    for (int ii = 0; ii < IQ; ii += 4) {
        float xk[4];
#pragma unroll
        for (int j = 0; j < 4; ++j) xk[j] = nx[j];
        if (ii + 4 < IQ) {   // uniform branch; 1-chunk-deep x prefetch
#pragma unroll
            for (int j = 0; j < 4; ++j)
                nx[j] = XT ? xc[(size_t)(ii + 4 + j) * B_TOT]
                           : xrow[ii + 4 + j];
        }

        // weight chunk: 16x s_load_dwordx4 at imm offsets from wbase
        float4 wt[O_T];
#pragma unroll
        for (int k = 0; k < O_T; ++k)
            wt[k] = *reinterpret_cast<const float4*>(wbase + k * LDW + ii);

        // wt[k].xy = i-pair A weights for row k, wt[k].zw = pair B
        const v2f* w2 = reinterpret_cast<const v2f*>(&wt[0]);

        // two packed sign-twisted chains (A: i0,i1; B: i2,i3)
        const v2f xvA = {xk[0], xk[1]}, xvB = {xk[2], xk[3]};
        const v2f dxA = xvA * delta,  dxB = xvB * delta;
        const v2f a0A = xvA * g1,     a0B = xvB * g1;
        const v2f a1A = xvA * gp1,    a1B = xvB * gp1;
        v2f cA, cB, t0A, t0B, t1A, t1B;
        cA.x  = __builtin_amdgcn_cosf(dxA.x);
        cB.x  = __builtin_amdgcn_cosf(dxB.x);
        cA.y  = __builtin_amdgcn_cosf(dxA.y);
        cB.y  = __builtin_amdgcn_cosf(dxB.y);
        t0A.x = __builtin_amdgcn_sinf(a0A.x);   // t0 = s0 (sigma_0 = +)
        t0B.x = __builtin_amdgcn_sinf(a0B.x);
        t0A.y = __builtin_amdgcn_sinf(a0A.y);
        t0B.y = __builtin_amdgcn_sinf(a0B.y);
        t1A.x = __builtin_amdgcn_sinf(a1A.x);   // t1 = s1 (sigma_1 = +)
        t1B.x = __builtin_amdgcn_sinf(a1B.x);
        t1A.y = __builtin_amdgcn_sinf(a1A.y);
        t1B.y = __builtin_amdgcn_sinf(a1B.y);
        const v2f c2A  = cA + cA,  c2B  = cB + cB;     // setup (pk_add)
        const v2f nc2A = -c2A,     nc2B = -c2B;        // setup only, not in chain

        // k = 0, 1: seeds
        acc[0] = __builtin_elementwise_fma(w2[0], t0A, acc[0]);
        acc[0] = __builtin_elementwise_fma(w2[1], t0B, acc[0]);
        acc[1] = __builtin_elementwise_fma(w2[2], t1A, acc[1]);
        acc[1] = __builtin_elementwise_fma(w2[3], t1B, acc[1]);

        // k = 2..15: t_k = fma(C, t_{k-1}, t_{k-2}), C = c2 if k odd, -c2 if
        // k even (sign-twist: t_k = sigma_k*s_k, sigma_k = (-1)^(k/2)).
        // Pure fma chain, NO fneg -> v_pk_fma_f32 has no emission excuse.
#pragma unroll
        for (int k = 2; k < O_T; ++k) {
            const v2f CA = (k & 1) ? c2A : nc2A;
            const v2f CB = (k & 1) ? c2B : nc2B;
            const v2f tnA = __builtin_elementwise_fma(CA, t1A, t0A);
            const v2f tnB = __builtin_elementwise_fma(CB, t1B, t0B);
            acc[k] = __builtin_elementwise_fma(w2[2 * k],     tnA, acc[k]);
            acc[k] = __builtin_elementwise_fma(w2[2 * k + 1], tnB, acc[k]);
            t0A = t1A; t1A = tnA;
            t0B = t1B; t1B = tnB;
        }
    }

    // cross-wave reduction; undo the sign twist here (sigma_k compile-time)
#pragma unroll
    for (int k = 0; k < O_T; ++k) {
        const float s = acc[k].x + acc[k].y;
        red[iq][lane][k] = ((k >> 1) & 1) ? -s : s;   // sigma_k
    }
    __syncthreads();

    // epilogue: 512 threads -> 64 b x 16 k = 1024 outputs, 2 per thread;
    // fold bias column (xb = 1)
    {
        const int b  = tid & 63;
        const int k2 = tid >> 6;           // 0..7 -> k = 2*k2, 2*k2+1
        float2 res;
        float* rp = &res.x;
#pragma unroll
        for (int kk = 0; kk < 2; ++kk) {
            const int k = k2 * 2 + kk;
            float s = 0.0f;
#pragma unroll
            for (int p = 0; p < WAVES; ++p) s += red[p][b][k];
            const int o = o0 + k;
            const float gb = w[(size_t)o * LDW + IN_D] * inv2pi;  // (0,1] rev
            s = fmaf(weight[(size_t)o * LDW + IN_D],
                     __builtin_amdgcn_sinf(gb), s);
            rp[kk] = s;
        }
        *reinterpret_cast<float2*>(
            out + (size_t)(b0 + b) * OUT_D + o0 + k2 * 2) = res;
    }
}

extern "C" void kernel_launch(void* const* d_in, const int* in_sizes, int n_in,
                              void* d_out, int out_size, void* d_ws, size_t ws_size,
                              hipStream_t stream) {
    const float* x      = (const float*)d_in[0];
    const float* weight = (const float*)d_in[1];
    const float* w      = (const float*)d_in[2];
    float* out          = (float*)d_out;

    dim3 grid(OUT_D / O_T, B_TOT / 64);   // (32, 16) = 512 blocks x 512 thr

    if (ws_size >= (size_t)IN_D * B_TOT * sizeof(float)) {
        float* xT = (float*)d_ws;
        dim3 tg(IN_D / 64, B_TOT / 64);   // (8, 16)
        xpose_kernel<<<tg, 256, 0, stream>>>(x, xT);
        skan_kernel<true><<<grid, 512, 0, stream>>>(xT, weight, w, out);
    } else {
        skan_kernel<false><<<grid, 512, 0, stream>>>(x, weight, w, out);
    }
}

// Round 17
// 27.694 us; speedup vs baseline: 1.2300x; 1.0041x over previous
//
#include <hip/hip_runtime.h>

// y[b,o] = sum_i weight[o,i] * sin(w[o,i] * xb[b,i]),  xb = [x | 1]
// w[o,i] = (o+1)*2pi/512 const across i. In REVOLUTIONS (v_sin_f32 native):
// arg = (o+1)/512 * x, |arg| <= ~5 << 256, so no v_fract (validated R1-R16).
//
// Sign-twisted Chebyshev recurrence (R16, absmax 0.0039):
//   t_k = sigma_k*s_k, sigma_k=(-1)^(k/2);  t_{k+1} = fma(+-c2, t_k, t_{k-1})
//   (pure fma chain, no fneg; sigma folded into epilogue).
//
// R17 = R16 + ONE lever: FORCE v_pk_fma_f32 via inline asm. Evidence the
// ext_vector "packed" chain was scalarized: VALUBusy ~40-55% across rounds
// = 2-3x the packed-issue model (which predicts ~15%); R13's gain was only
// 10% not the predicted 40%. Wrappers emit exactly one VOP3P per fma;
// weight pair rides as the single 64-bit SGPR operand (s_load result,
// Tensile-style). Non-volatile asm -> scheduler can still hoist s_loads.

#define B_TOT 1024
#define IN_D  512
#define OUT_D 512
#define LDW   513              // IN+1
#define O_T   16               // outputs per block (15 recurrence steps)
#define WAVES 8                // i-eighths per block
#define IQ    (IN_D / WAVES)   // 64 i's per wave

typedef float v2f __attribute__((ext_vector_type(2)));

// one VOP3P instruction, all-VGPR operands (recurrence step)
__device__ __forceinline__ v2f pk_fma_vvv(v2f a, v2f b, v2f c) {
    v2f d;
    asm("v_pk_fma_f32 %0, %1, %2, %3" : "=v"(d) : "v"(a), "v"(b), "v"(c));
    return d;
}
// one VOP3P instruction, weight pair as the single 64-bit SGPR operand
__device__ __forceinline__ v2f pk_fma_svv(v2f a_s, v2f b, v2f c) {
    v2f d;
    asm("v_pk_fma_f32 %0, %1, %2, %3" : "=v"(d) : "s"(a_s), "v"(b), "v"(c));
    return d;
}

// ---- transpose pre-pass: xT[i][b] = x[b][i], 64x64 LDS tiles ----
__global__ __launch_bounds__(256)
void xpose_kernel(const float* __restrict__ x, float* __restrict__ xT)
{
    __shared__ float t[64][65];
    const int i0 = blockIdx.x * 64;
    const int b0 = blockIdx.y * 64;
    const int c  = threadIdx.x & 63;
    const int r0 = threadIdx.x >> 6;   // 0..3
#pragma unroll
    for (int rr = 0; rr < 64; rr += 4) {
        const int r = rr + r0;
        t[r][c] = x[(size_t)(b0 + r) * IN_D + i0 + c];   // coalesced along i
    }
    __syncthreads();
#pragma unroll
    for (int rr = 0; rr < 64; rr += 4) {
        const int r = rr + r0;
        xT[(size_t)(i0 + r) * B_TOT + b0 + c] = t[c][r]; // coalesced along b
    }
}

// ---- main kernel; XT = x transposed in d_ws (coalesced reads) ----
template <bool XT>
__global__ __launch_bounds__(512, 4)
void skan_kernel(const float* __restrict__ x,
                 const float* __restrict__ weight,
                 const float* __restrict__ w,
                 float* __restrict__ out)
{
    __shared__ float red[WAVES][64][O_T + 1];   // 34.8 KB; stride 17 (2-way max)

    const int tid  = threadIdx.x;
    const int lane = tid & 63;
    const int b0   = blockIdx.y * 64;
    const int o0   = blockIdx.x * O_T;   // uniform (SGPR) by construction
    const int iq   = __builtin_amdgcn_readfirstlane(tid >> 6);
    const int i0   = iq * IQ;

    const float inv2pi = 0.15915493667125702f;
    // frequencies from w (don't assume the ramp): g1=(o0+1)/512, delta=1/512
    const float g1    = w[(size_t)o0 * LDW] * inv2pi;
    const float delta = w[(size_t)(o0 + 1) * LDW] * inv2pi - g1;
    const float gp1   = g1 + delta;      // frequency for k = 1

    // ONE scalar base; all weight accesses are imm offsets -> s_load_dwordx4
    const float* __restrict__ wbase = weight + (size_t)o0 * LDW + i0;

    // XT path: consecutive lanes -> consecutive addresses (one 256B txn)
    const float* __restrict__ xc   = x + (size_t)i0 * B_TOT + b0 + lane;
    // fallback path: own-row reads
    const float* __restrict__ xrow = x + (size_t)(b0 + lane) * IN_D + i0;

    v2f acc[O_T];   // packed over i-pairs; both halves are partial i-sums
#pragma unroll
    for (int k = 0; k < O_T; ++k) acc[k] = (v2f)0.0f;

    float nx[4];
#pragma unroll
    for (int j = 0; j < 4; ++j)
        nx[j] = XT ? xc[(size_t)j * B_TOT] : xrow[j];

    for (int ii = 0; ii < IQ; ii += 4) {
        float xk[4];
#pragma unroll
        for (int j = 0; j < 4; ++j) xk[j] = nx[j];
        if (ii + 4 < IQ) {   // uniform branch; 1-chunk-deep x prefetch
#pragma unroll
            for (int j = 0; j < 4; ++j)
                nx[j] = XT ? xc[(size_t)(ii + 4 + j) * B_TOT]
                           : xrow[ii + 4 + j];
        }

        // weight chunk: 16x s_load_dwordx4 at imm offsets from wbase
        float4 wt[O_T];
#pragma unroll
        for (int k = 0; k < O_T; ++k)
            wt[k] = *reinterpret_cast<const float4*>(wbase + k * LDW + ii);

        // wt[k].xy = i-pair A weights for row k, wt[k].zw = pair B
        const v2f* w2 = reinterpret_cast<const v2f*>(&wt[0]);

        // two packed sign-twisted chains (A: i0,i1; B: i2,i3)
        const v2f xvA = {xk[0], xk[1]}, xvB = {xk[2], xk[3]};
        const v2f dxA = xvA * delta,  dxB = xvB * delta;
        const v2f a0A = xvA * g1,     a0B = xvB * g1;
        const v2f a1A = xvA * gp1,    a1B = xvB * gp1;
        v2f cA, cB, t0A, t0B, t1A, t1B;
        cA.x  = __builtin_amdgcn_cosf(dxA.x);
        cB.x  = __builtin_amdgcn_cosf(dxB.x);
        cA.y  = __builtin_amdgcn_cosf(dxA.y);
        cB.y  = __builtin_amdgcn_cosf(dxB.y);
        t0A.x = __builtin_amdgcn_sinf(a0A.x);   // t0 = s0 (sigma_0 = +)
        t0B.x = __builtin_amdgcn_sinf(a0B.x);
        t0A.y = __builtin_amdgcn_sinf(a0A.y);
        t0B.y = __builtin_amdgcn_sinf(a0B.y);
        t1A.x = __builtin_amdgcn_sinf(a1A.x);   // t1 = s1 (sigma_1 = +)
        t1B.x = __builtin_amdgcn_sinf(a1B.x);
        t1A.y = __builtin_amdgcn_sinf(a1A.y);
        t1B.y = __builtin_amdgcn_sinf(a1B.y);
        const v2f c2A  = cA + cA,  c2B  = cB + cB;   // setup
        const v2f nc2A = -c2A,     nc2B = -c2B;      // setup only

        // k = 0, 1: seeds (forced v_pk_fma_f32, SGPR weight operand)
        acc[0] = pk_fma_svv(w2[0], t0A, acc[0]);
        acc[0] = pk_fma_svv(w2[1], t0B, acc[0]);
        acc[1] = pk_fma_svv(w2[2], t1A, acc[1]);
        acc[1] = pk_fma_svv(w2[3], t1B, acc[1]);

        // k = 2..15: t_k = pk_fma(C, t_{k-1}, t_{k-2}), C in {c2, -c2};
        // acc_k = pk_fma(w_k, t_k, acc_k). 4 forced VOP3P per k.
#pragma unroll
        for (int k = 2; k < O_T; ++k) {
            const v2f CA = (k & 1) ? c2A : nc2A;
            const v2f CB = (k & 1) ? c2B : nc2B;
            const v2f tnA = pk_fma_vvv(CA, t1A, t0A);
            const v2f tnB = pk_fma_vvv(CB, t1B, t0B);
            acc[k] = pk_fma_svv(w2[2 * k],     tnA, acc[k]);
            acc[k] = pk_fma_svv(w2[2 * k + 1], tnB, acc[k]);
            t0A = t1A; t1A = tnA;
            t0B = t1B; t1B = tnB;
        }
    }

    // cross-wave reduction; undo the sign twist here (sigma_k compile-time)
#pragma unroll
    for (int k = 0; k < O_T; ++k) {
        const float s = acc[k].x + acc[k].y;
        red[iq][lane][k] = ((k >> 1) & 1) ? -s : s;   // sigma_k
    }
    __syncthreads();

    // epilogue: 512 threads -> 64 b x 16 k = 1024 outputs, 2 per thread;
    // fold bias column (xb = 1)
    {
        const int b  = tid & 63;
        const int k2 = tid >> 6;           // 0..7 -> k = 2*k2, 2*k2+1
        float2 res;
        float* rp = &res.x;
#pragma unroll
        for (int kk = 0; kk < 2; ++kk) {
            const int k = k2 * 2 + kk;
            float s = 0.0f;
#pragma unroll
            for (int p = 0; p < WAVES; ++p) s += red[p][b][k];
            const int o = o0 + k;
            const float gb = w[(size_t)o * LDW + IN_D] * inv2pi;  // (0,1] rev
            s = fmaf(weight[(size_t)o * LDW + IN_D],
                     __builtin_amdgcn_sinf(gb), s);
            rp[kk] = s;
        }
        *reinterpret_cast<float2*>(
            out + (size_t)(b0 + b) * OUT_D + o0 + k2 * 2) = res;
    }
}

extern "C" void kernel_launch(void* const* d_in, const int* in_sizes, int n_in,
                              void* d_out, int out_size, void* d_ws, size_t ws_size,
                              hipStream_t stream) {
    const float* x      = (const float*)d_in[0];
    const float* weight = (const float*)d_in[1];
    const float* w      = (const float*)d_in[2];
    float* out          = (float*)d_out;

    dim3 grid(OUT_D / O_T, B_TOT / 64);   // (32, 16) = 512 blocks x 512 thr

    if (ws_size >= (size_t)IN_D * B_TOT * sizeof(float)) {
        float* xT = (float*)d_ws;
        dim3 tg(IN_D / 64, B_TOT / 64);   // (8, 16)
        xpose_kernel<<<tg, 256, 0, stream>>>(x, xT);
        skan_kernel<true><<<grid, 512, 0, stream>>>(xT, weight, w, out);
    } else {
        skan_kernel<false><<<grid, 512, 0, stream>>>(x, weight, w, out);
    }
}

// Round 18
// 27.467 us; speedup vs baseline: 1.2402x; 1.0083x over previous
//
#include <hip/hip_runtime.h>

// y[b,o] = sum_i weight[o,i] * sin(w[o,i] * xb[b,i]),  xb = [x | 1]
// w[o,i] = (o+1)*2pi/512 const across i. In REVOLUTIONS (v_sin_f32 native):
// arg = (o+1)/512 * x, |arg| <= ~5 << 256, so no v_fract (validated R1-R17).
//
// Chebyshev phase recurrence across o (validated R5-R17):
//   s_{k+1} = 2*cos(dx)*s_k - s_{k-1},  dx = delta*x   (absmax 0.0078 @ 15)
//
// R18 = R13 (champion, 27.05us) + ONE lever: per-wave start STAGGER.
// R17's forced-pk null proved the issue stream is already packed (~6-7us
// issue/SIMD) -> ~60% of time is stall, insensitive to occupancy / x layout
// / weight pipe / packing / scheduling (R6-R17). Last untested mechanism:
// phase-locked waves drain lgkmcnt(0) SIMULTANEOUSLY each chunk (identical
// code, identical start), so the SIMD idles through every drain and extra
// waves deepen the same idle (R6 null ✓). Stagger wave iq by ~64*iq cy
// (s_sleep(1) x iq, max ~450cy ~= one chunk period) -> drains interleave,
// other waves' compute fills them. R12 bundled a stagger with two
// regressions; this is the clean isolated test.

#define B_TOT 1024
#define IN_D  512
#define OUT_D 512
#define LDW   513              // IN+1
#define O_T   16               // outputs per block (15 recurrence steps)
#define WAVES 8                // i-eighths per block
#define IQ    (IN_D / WAVES)   // 64 i's per wave

typedef float v2f __attribute__((ext_vector_type(2)));

// ---- transpose pre-pass: xT[i][b] = x[b][i], 64x64 LDS tiles ----
__global__ __launch_bounds__(256)
void xpose_kernel(const float* __restrict__ x, float* __restrict__ xT)
{
    __shared__ float t[64][65];
    const int i0 = blockIdx.x * 64;
    const int b0 = blockIdx.y * 64;
    const int c  = threadIdx.x & 63;
    const int r0 = threadIdx.x >> 6;   // 0..3
#pragma unroll
    for (int rr = 0; rr < 64; rr += 4) {
        const int r = rr + r0;
        t[r][c] = x[(size_t)(b0 + r) * IN_D + i0 + c];   // coalesced along i
    }
    __syncthreads();
#pragma unroll
    for (int rr = 0; rr < 64; rr += 4) {
        const int r = rr + r0;
        xT[(size_t)(i0 + r) * B_TOT + b0 + c] = t[c][r]; // coalesced along b
    }
}

// ---- main kernel; XT = x transposed in d_ws (coalesced reads) ----
template <bool XT>
__global__ __launch_bounds__(512, 4)
void skan_kernel(const float* __restrict__ x,
                 const float* __restrict__ weight,
                 const float* __restrict__ w,
                 float* __restrict__ out)
{
    __shared__ float red[WAVES][64][O_T + 1];   // 34.8 KB; stride 17 (2-way max)

    const int tid  = threadIdx.x;
    const int lane = tid & 63;
    const int b0   = blockIdx.y * 64;
    const int o0   = blockIdx.x * O_T;   // uniform (SGPR) by construction
    const int iq   = __builtin_amdgcn_readfirstlane(tid >> 6);
    const int i0   = iq * IQ;

    // R18 lever: de-phase the block's waves so per-chunk lgkmcnt(0) drains
    // interleave across waves instead of hitting the SIMD simultaneously.
    for (int t = 0; t < iq; ++t) __builtin_amdgcn_s_sleep(1);

    const float inv2pi = 0.15915493667125702f;
    // frequencies from w (don't assume the ramp): g1=(o0+1)/512, delta=1/512
    const float g1    = w[(size_t)o0 * LDW] * inv2pi;
    const float delta = w[(size_t)(o0 + 1) * LDW] * inv2pi - g1;
    const float gp    = g1 - delta;      // phase for k = -1

    // ONE scalar base; all weight accesses are imm offsets -> s_load_dwordx4
    const float* __restrict__ wbase = weight + (size_t)o0 * LDW + i0;

    // XT path: consecutive lanes -> consecutive addresses (one 256B txn)
    const float* __restrict__ xc   = x + (size_t)i0 * B_TOT + b0 + lane;
    // fallback path: own-row reads
    const float* __restrict__ xrow = x + (size_t)(b0 + lane) * IN_D + i0;

    v2f acc[O_T];   // packed over i-pairs; .x and .y are both partial i-sums
#pragma unroll
    for (int k = 0; k < O_T; ++k) acc[k] = (v2f)0.0f;

    float nx[4];
#pragma unroll
    for (int j = 0; j < 4; ++j)
        nx[j] = XT ? xc[(size_t)j * B_TOT] : xrow[j];

    for (int ii = 0; ii < IQ; ii += 4) {
        float xk[4];
#pragma unroll
        for (int j = 0; j < 4; ++j) xk[j] = nx[j];
        if (ii + 4 < IQ) {   // uniform branch; 1-chunk-deep x prefetch
#pragma unroll
            for (int j = 0; j < 4; ++j)
                nx[j] = XT ? xc[(size_t)(ii + 4 + j) * B_TOT]
                           : xrow[ii + 4 + j];
        }

        // weight chunk: 16x s_load_dwordx4 at imm offsets from wbase
        float4 wt[O_T];
#pragma unroll
        for (int k = 0; k < O_T; ++k)
            wt[k] = *reinterpret_cast<const float4*>(wbase + k * LDW + ii);

        // two packed chains: i-pair (xk0,xk1) and (xk2,xk3)
#pragma unroll
        for (int p = 0; p < 2; ++p) {
            const v2f xv = p ? (v2f){xk[2], xk[3]} : (v2f){xk[0], xk[1]};
            const v2f dxv = xv * delta;                       // v_pk_mul
            v2f cv, sc, sp;
            cv.x = __builtin_amdgcn_cosf(dxv.x);              // v_cos x2
            cv.y = __builtin_amdgcn_cosf(dxv.y);
            const v2f c2 = cv + cv;                           // v_pk_add
            const v2f a1 = xv * g1, ap = xv * gp;             // v_pk_mul x2
            sc.x = __builtin_amdgcn_sinf(a1.x);               // v_sin x4
            sc.y = __builtin_amdgcn_sinf(a1.y);
            sp.x = __builtin_amdgcn_sinf(ap.x);
            sp.y = __builtin_amdgcn_sinf(ap.y);

            {   // k = 0
                const v2f wp = p ? (v2f){wt[0].z, wt[0].w}
                                 : (v2f){wt[0].x, wt[0].y};
                acc[0] = __builtin_elementwise_fma(wp, sc, acc[0]);
            }
#pragma unroll
            for (int k = 1; k < O_T; ++k) {
                const v2f sn = __builtin_elementwise_fma(c2, sc, -sp);
                const v2f wp = p ? (v2f){wt[k].z, wt[k].w}    // consecutive
                                 : (v2f){wt[k].x, wt[k].y};   // SGPR pair
                acc[k] = __builtin_elementwise_fma(wp, sn, acc[k]);
                sp = sc; sc = sn;
            }
        }
    }

    // cross-wave reduction (the only barrier in the kernel)
#pragma unroll
    for (int k = 0; k < O_T; ++k) red[iq][lane][k] = acc[k].x + acc[k].y;
    __syncthreads();

    // epilogue: 512 threads -> 64 b x 16 k = 1024 outputs, 2 per thread;
    // fold bias column (xb = 1)
    {
        const int b  = tid & 63;
        const int k2 = tid >> 6;           // 0..7 -> k = 2*k2, 2*k2+1
        float2 res;
        float* rp = &res.x;
#pragma unroll
        for (int kk = 0; kk < 2; ++kk) {
            const int k = k2 * 2 + kk;
            float s = 0.0f;
#pragma unroll
            for (int p = 0; p < WAVES; ++p) s += red[p][b][k];
            const int o = o0 + k;
            const float gb = w[(size_t)o * LDW + IN_D] * inv2pi;  // (0,1] rev
            s = fmaf(weight[(size_t)o * LDW + IN_D],
                     __builtin_amdgcn_sinf(gb), s);
            rp[kk] = s;
        }
        *reinterpret_cast<float2*>(
            out + (size_t)(b0 + b) * OUT_D + o0 + k2 * 2) = res;
    }
}

extern "C" void kernel_launch(void* const* d_in, const int* in_sizes, int n_in,
                              void* d_out, int out_size, void* d_ws, size_t ws_size,
                              hipStream_t stream) {
    const float* x      = (const float*)d_in[0];
    const float* weight = (const float*)d_in[1];
    const float* w      = (const float*)d_in[2];
    float* out          = (float*)d_out;

    dim3 grid(OUT_D / O_T, B_TOT / 64);   // (32, 16) = 512 blocks x 512 thr

    if (ws_size >= (size_t)IN_D * B_TOT * sizeof(float)) {
        float* xT = (float*)d_ws;
        dim3 tg(IN_D / 64, B_TOT / 64);   // (8, 16)
        xpose_kernel<<<tg, 256, 0, stream>>>(x, xT);
        skan_kernel<true><<<grid, 512, 0, stream>>>(xT, weight, w, out);
    } else {
        skan_kernel<false><<<grid, 512, 0, stream>>>(x, weight, w, out);
    }
}